// Round 7
// baseline (211.482 us; speedup 1.0000x reference)
//
#include <hip/hip_runtime.h>
#include <hip/hip_bf16.h>
#include <math.h>

#define BQ   2      // batch
#define NN   1024   // seq len
#define DMD  512    // d_model
#define NH   8      // heads
#define DKK  64     // head dim
#define NSEL 5      // NB+1 block values (0..4)
#define NCLS 17     // block-pair classes
#define NP   1344   // padded per-batch capacity (buckets padded to 64)
#define NPT  21     // NP/64 tiles
#define MAXT 6      // max key-tiles per wave in k_attn (ceil(21/4))
#define SSp  1348   // S row stride (shorts): 4-row stride = 2696 dwords = 8 mod 32 -> conflict-free P writes

typedef __attribute__((ext_vector_type(8))) short bf16x8;
typedef __attribute__((ext_vector_type(8))) unsigned short u16x8;
typedef __attribute__((ext_vector_type(4))) float f32x4;

__device__ __forceinline__ int clsOf(int r, int c) { return (r == 0 || c == 0) ? 0 : ((r - 1) * 4 + c); }

__device__ __forceinline__ unsigned short f2bf(float x) {
    __hip_bfloat16 h = __float2bfloat16(x);
    return *reinterpret_cast<unsigned short*>(&h);
}

// ---------------------------------------------------------------- setup (bucketing only)
__global__ __launch_bounds__(256) void k_setup(
    const void* __restrict__ b_seq_r, const void* __restrict__ mask_r,
    int* __restrict__ maskI, int* __restrict__ perm, int* __restrict__ rowc,
    int* __restrict__ startPad, int* __restrict__ maskP)
{
    __shared__ int det[5];
    __shared__ int cnts[BQ][NSEL];
    __shared__ int offs[BQ][NSEL];
    __shared__ int sstart[BQ][NSEL + 1];
    int tid = threadIdx.x;
    if (tid < 5) det[tid] = 0;
    if (tid < BQ * NSEL) { cnts[tid / NSEL][tid % NSEL] = 0; offs[tid / NSEL][tid % NSEL] = 0; }
    __syncthreads();
    const int* b32 = (const int*)b_seq_r;
    const unsigned char* mb = (const unsigned char*)mask_r;
    const int* m32 = (const int*)mask_r;
    if (tid < 64) {
        if (b32[2 * tid + 1] != 0) atomicOr(&det[0], 1);
        if (b32[2 * tid] != 0)     atomicOr(&det[1], 1);
        if (m32[2 * tid + 1] != 0) atomicOr(&det[3], 1);
        if (m32[2 * tid] != 0)     atomicOr(&det[4], 1);
    }
    if ((tid & 3) != 0 && mb[tid] != 0) atomicOr(&det[2], 1);
    __syncthreads();
    int bsI64 = (det[0] == 0 && det[1] != 0);
    int mk = det[2] ? 1 : ((det[3] == 0 && det[4] != 0) ? 2 : 0);

    for (int g = tid; g < BQ * NN; g += 256) {
        int m = (mk == 1) ? (mb[g] != 0) : ((mk == 2) ? (m32[2 * g] != 0) : (m32[g] != 0));
        maskI[g] = m;
        int bs = bsI64 ? b32[2 * g] : b32[g];
        bs = bs < 0 ? 0 : (bs > 4 ? 4 : bs);
        atomicAdd(&cnts[g / NN][bs], 1);
    }
    __syncthreads();
    if (tid == 0) {
        for (int b = 0; b < BQ; b++) {
            int acc = 0;
            for (int c = 0; c < NSEL; c++) {
                sstart[b][c] = acc;
                acc += ((cnts[b][c] + 63) / 64) * 64;
            }
            sstart[b][NSEL] = acc;
            for (int c = 0; c <= NSEL; c++) startPad[b * (NSEL + 1) + c] = sstart[b][c];
        }
    }
    __syncthreads();
    for (int g = tid; g < BQ * NP; g += 256) {
        perm[g] = -1;
        int b = g / NP, sslot = g % NP;
        int c = 0;
        for (int cc = 1; cc < NSEL; cc++) if (sslot >= sstart[b][cc]) c = cc;
        rowc[g] = c;
    }
    __syncthreads();
    for (int g = tid; g < BQ * NN; g += 256) {
        int b = g / NN, n = g % NN;
        int bs = bsI64 ? b32[2 * g] : b32[g];
        bs = bs < 0 ? 0 : (bs > 4 ? 4 : bs);
        int pos = sstart[b][bs] + atomicAdd(&offs[b][bs], 1);
        perm[b * NP + pos] = n;
    }
    __syncthreads();
    for (int g = tid; g < BQ * NP; g += 256) {
        int tok = perm[g];
        maskP[g] = (tok < 0) ? 2 : maskI[(g / NP) * NN + tok];
    }
}

// ---------------------------------------------------------------- prep: cast lin->Lt (960 blocks) + wmix (272 blocks)
__global__ __launch_bounds__(256) void k_prep(
    const float* __restrict__ lr, unsigned short* __restrict__ Lt,
    const float* __restrict__ W1, const float* __restrict__ W2,
    const float* __restrict__ al1, const float* __restrict__ al2,
    unsigned short* __restrict__ W1bt, unsigned short* __restrict__ W2bt)
{
    int bx = blockIdx.x;
    int tid = threadIdx.x;
    if (bx < 960) {
        // cast+transpose lin[ts][k][n] -> Lt[ts][n][k] bf16
        int ts = bx >> 6, rem = bx & 63;
        int kt = rem >> 3, nt = rem & 7;
        const float* src = lr + (size_t)ts * DMD * 512;
        unsigned short* dst = Lt + (size_t)ts * DMD * 512;
        __shared__ float Tf[64][68];
        int r = tid >> 2, c4 = tid & 3;
#pragma unroll
        for (int i = 0; i < 4; i++) {
            float4 v = *(const float4*)&src[(size_t)(kt * 64 + r) * 512 + nt * 64 + c4 * 16 + i * 4];
            *(float4*)&Tf[r][c4 * 16 + i * 4] = v;
        }
        __syncthreads();
        unsigned short tmp[16];
#pragma unroll
        for (int i = 0; i < 16; i++) tmp[i] = f2bf(Tf[c4 * 16 + i][r]);
        u16x8 o0, o1;
#pragma unroll
        for (int i = 0; i < 8; i++) { o0[i] = tmp[i]; o1[i] = tmp[8 + i]; }
        unsigned short* dp = &dst[(size_t)(nt * 64 + r) * 512 + kt * 64 + c4 * 16];
        *(u16x8*)&dp[0] = o0;
        *(u16x8*)&dp[8] = o1;
    } else {
        // wmix: W{1,2}bt[cls][h][n][m] = sum_B softmax(alpha)[B] * W[B][h][m][n]
        int bid = bx - 960;
        int w = bid / (NCLS * NH);
        int rem = bid % (NCLS * NH);
        int c = rem / NH, h = rem % NH;
        const float* W = w ? W2 : W1;
        const float* a = w ? al2 : al1;
        unsigned short* outp = (w ? W2bt : W1bt) + (((size_t)c * NH + h) << 12);
        float vals[4], mx = -1e30f;
#pragma unroll
        for (int bb = 0; bb < 4; bb++) { vals[bb] = a[(c * 4 + bb) * NH + h]; mx = fmaxf(mx, vals[bb]); }
        float ssum = 0.f;
#pragma unroll
        for (int bb = 0; bb < 4; bb++) { vals[bb] = __expf(vals[bb] - mx); ssum += vals[bb]; }
        float inv = 1.0f / ssum;
        float s0 = vals[0] * inv, s1 = vals[1] * inv, s2 = vals[2] * inv, s3 = vals[3] * inv;
        const float* p0 = W + (size_t)(0 * NH + h) * 4096;
        const float* p1 = W + (size_t)(1 * NH + h) * 4096;
        const float* p2 = W + (size_t)(2 * NH + h) * 4096;
        const float* p3 = W + (size_t)(3 * NH + h) * 4096;
        for (int e = tid; e < 4096; e += 256) {
            float v = s0 * p0[e] + s1 * p1[e] + s2 * p2[e] + s3 * p3[e];
            int mm = e >> 6, nn = e & 63;
            outp[nn * 64 + mm] = f2bf(v);     // transposed store
        }
    }
}

// ---------------------------------------------------------------- bucketed QKV projection, MFMA bf16
// grid (21 tiles, 4 hk-quarters, B*3), block 256. Output all row-major: Qb/Kb/Vb[b][h][ip][64].
__global__ __launch_bounds__(256) void k_proj(
    const float* __restrict__ qr, const float* __restrict__ kr, const float* __restrict__ vr,
    const unsigned short* __restrict__ Lt,
    const int* __restrict__ perm, const int* __restrict__ rowc, const int* __restrict__ startPad,
    unsigned short* __restrict__ Qb, unsigned short* __restrict__ Kb, unsigned short* __restrict__ Vb)
{
    int ti = blockIdx.x;
    int qtr = blockIdx.y;
    int bt = blockIdx.z;
    int b = bt / 3, t = bt % 3;
    int nTot = startPad[b * (NSEL + 1) + NSEL];
    if (ti * 64 >= nTot) return;
    int sel = rowc[b * NP + ti * 64];
    const float* X = (t == 0) ? qr : ((t == 1) ? kr : vr);
    const unsigned short* L = Lt + (size_t)(t * NSEL + sel) * DMD * 512;   // [n][k] bf16

    __shared__ __align__(16) unsigned short Xb[64][72];
    __shared__ __align__(16) unsigned short Lb[128][72];
    __shared__ int toks[64];

    int tid = threadIdx.x;
    int wave = tid >> 6, lane = tid & 63;
    int m = lane & 15, q = lane >> 4;
    if (tid < 64) toks[tid] = perm[b * NP + ti * 64 + tid];
    f32x4 acc[4][2];
#pragma unroll
    for (int mt = 0; mt < 4; mt++) { acc[mt][0] = {0, 0, 0, 0}; acc[mt][1] = {0, 0, 0, 0}; }
    __syncthreads();

    for (int kb = 0; kb < DMD; kb += 64) {
        {
            int r = tid >> 2, c0 = (tid & 3) * 16;
            int tok = toks[r];
            unsigned short tmp[16];
            if (tok >= 0) {
                const float* xp = &X[((size_t)b * NN + tok) * DMD + kb + c0];
#pragma unroll
                for (int i = 0; i < 16; i += 4) {
                    float4 v = *(const float4*)&xp[i];
                    tmp[i] = f2bf(v.x); tmp[i + 1] = f2bf(v.y);
                    tmp[i + 2] = f2bf(v.z); tmp[i + 3] = f2bf(v.w);
                }
            } else {
#pragma unroll
                for (int i = 0; i < 16; i++) tmp[i] = 0;
            }
            u16x8 o0, o1;
#pragma unroll
            for (int i = 0; i < 8; i++) { o0[i] = tmp[i]; o1[i] = tmp[8 + i]; }
            *(u16x8*)&Xb[r][c0] = o0;
            *(u16x8*)&Xb[r][c0 + 8] = o1;
        }
        {
            int n = tid >> 1, hf = tid & 1;
            const unsigned short* lp = &L[(size_t)(qtr * 128 + n) * 512 + kb + hf * 32];
#pragma unroll
            for (int s = 0; s < 4; s++)
                *(u16x8*)&Lb[n][hf * 32 + s * 8] = *(const u16x8*)&lp[s * 8];
        }
        __syncthreads();
#pragma unroll
        for (int kc = 0; kc < 64; kc += 32) {
            bf16x8 bf0 = *(const bf16x8*)&Lb[wave * 32 + m][kc + q * 8];
            bf16x8 bf1 = *(const bf16x8*)&Lb[wave * 32 + 16 + m][kc + q * 8];
#pragma unroll
            for (int mt = 0; mt < 4; mt++) {
                bf16x8 a = *(const bf16x8*)&Xb[mt * 16 + m][kc + q * 8];
                acc[mt][0] = __builtin_amdgcn_mfma_f32_16x16x32_bf16(a, bf0, acc[mt][0], 0, 0, 0);
                acc[mt][1] = __builtin_amdgcn_mfma_f32_16x16x32_bf16(a, bf1, acc[mt][1], 0, 0, 0);
            }
        }
        __syncthreads();
    }

    unsigned short* O = (t == 0) ? Qb : ((t == 1) ? Kb : Vb);
#pragma unroll
    for (int mt = 0; mt < 4; mt++)
#pragma unroll
        for (int nt = 0; nt < 2; nt++)
#pragma unroll
            for (int g = 0; g < 4; g++) {
                int i = mt * 16 + q * 4 + g;
                int hk = qtr * 128 + wave * 32 + nt * 16 + m;
                int h = hk >> 6, k0 = hk & 63;
                O[(((size_t)b * NH + h) * NP + ti * 64 + i) * 64 + k0] = f2bf(acc[mt][nt][g]);
            }
}

// ---------------------------------------------------------------- Q2/V2t precompute, MFMA
// type 0: Q2[c][bh][ip][n] = sum_m Qb[ip][m] * W1bt[cls(r(ip),c)][n][m]
// type 1: V2t[r][bh][k][jp] = sum_d W2bt[cls(r,c(jp))][k][d] * Vb[jp][d]
__global__ __launch_bounds__(256) void k_qv2(
    const unsigned short* __restrict__ Qb, const unsigned short* __restrict__ Vb,
    const unsigned short* __restrict__ W1bt, const unsigned short* __restrict__ W2bt,
    const int* __restrict__ rowc, const int* __restrict__ startPad,
    unsigned short* __restrict__ Q2, unsigned short* __restrict__ V2t)
{
    int ti = blockIdx.x;              // 21
    int cv = blockIdx.y;              // 5: c (type0) / r (type1)
    int zz = blockIdx.z;              // 32: type*16 + bh
    int type = zz >> 4, bh = zz & 15;
    int b = bh >> 3, h = bh & 7;
    int nTot = startPad[b * (NSEL + 1) + NSEL];
    if (ti * 64 >= nTot) return;
    int tb = rowc[b * NP + ti * 64];
    int tid = threadIdx.x;
    int wave = tid >> 6, lane = tid & 63;
    int m = lane & 15, q = lane >> 4;

    const unsigned short *A, *B;
    unsigned short* C;
    size_t cRow;
    if (type == 0) {
        int cls = clsOf(tb, cv);
        A = Qb + ((size_t)bh * NP + ti * 64) * 64;
        B = W1bt + (((size_t)cls * NH + h) << 12);
        C = Q2 + (((size_t)cv * 16 + bh) * NP + ti * 64) * 64;
        cRow = 64;
    } else {
        int cls = clsOf(cv, tb);
        A = W2bt + (((size_t)cls * NH + h) << 12);
        B = Vb + ((size_t)bh * NP + ti * 64) * 64;
        C = V2t + ((size_t)cv * 16 + bh) * 64 * NP + ti * 64;
        cRow = NP;
    }
    const unsigned short* bp = B + (size_t)(wave * 16 + m) * 64 + q * 8;
    bf16x8 b0 = *(const bf16x8*)bp;
    bf16x8 b1 = *(const bf16x8*)(bp + 32);
#pragma unroll
    for (int mb = 0; mb < 4; mb++) {
        const unsigned short* ap = A + (size_t)(mb * 16 + m) * 64 + q * 8;
        bf16x8 a0 = *(const bf16x8*)ap;
        bf16x8 a1 = *(const bf16x8*)(ap + 32);
        f32x4 acc = {0.f, 0.f, 0.f, 0.f};
        acc = __builtin_amdgcn_mfma_f32_16x16x32_bf16(a0, b0, acc, 0, 0, 0);
        acc = __builtin_amdgcn_mfma_f32_16x16x32_bf16(a1, b1, acc, 0, 0, 0);
#pragma unroll
        for (int g = 0; g < 4; g++)
            C[(size_t)(mb * 16 + q * 4 + g) * cRow + wave * 16 + m] = f2bf(acc[g]);
    }
}

// ---------------------------------------------------------------- fused attention: scores + softmax + PV only
// grid (NP/16, B*H), block 256 (4 waves), 3 blocks/CU (LDS ~44 KB).
__global__ __launch_bounds__(256, 3) void k_attn(
    const unsigned short* __restrict__ Q2, const unsigned short* __restrict__ Kb,
    const unsigned short* __restrict__ V2t,
    const int* __restrict__ perm, const int* __restrict__ rowc, const int* __restrict__ startPad,
    const int* __restrict__ maskI, const int* __restrict__ maskP,
    float* __restrict__ out)
{
    int it = blockIdx.x;
    int bh = blockIdx.y;
    int b = bh >> 3, h = bh & 7;
    int nTot = startPad[b * (NSEL + 1) + NSEL];
    int i0 = it * 16;
    if (i0 >= nTot) return;
    int r = rowc[b * NP + i0];
    int tiles = nTot >> 6;

    __shared__ unsigned short S[16][SSp];        // 43136 B: P (bf16)
    __shared__ float wred[4][16];
    __shared__ float wsum[4][16];
    __shared__ int tilec[NPT];
    __shared__ int mrow[16];
    __shared__ int toki[16];

    int tid = threadIdx.x;
    int wave = tid >> 6, lane = tid & 63;
    int m = lane & 15, q = lane >> 4;

    const int* permB = perm + b * NP;
    const unsigned short* KbB = Kb + (size_t)bh * NP * 64;
    const unsigned short* Q2B = Q2 + (size_t)bh * NP * 64;             // + c*16*NP*64
    const unsigned short* V2B = V2t + ((size_t)r * 16 + bh) * 64 * NP; // [k][jp]
    const int* maskPB = maskP + b * NP;

    if (tid < NPT) tilec[tid] = rowc[b * NP + tid * 64];
    else if (tid >= 64 && tid < 80) {
        int rr = tid - 64;
        int tok = permB[i0 + rr];
        toki[rr] = tok;
        mrow[rr] = (tok >= 0) ? maskI[b * NN + tok] : 0;
    }
    __syncthreads();

    // ---- phase 1: scores in registers
    float sarr[MAXT][4][4];
    float lmax[4] = {-INFINITY, -INFINITY, -INFINITY, -INFINITY};
    int mrow4[4];
#pragma unroll
    for (int g = 0; g < 4; g++) mrow4[g] = mrow[q * 4 + g];

#pragma unroll
    for (int tt = 0; tt < MAXT; tt++) {
        int jt = wave + tt * 4;
        bool valid = (jt < tiles);
        int jts = valid ? jt : 0;
        int c = tilec[jts];
        int jb = jts * 64;
        const unsigned short* qa = Q2B + (size_t)c * 16 * NP * 64 + (size_t)(i0 + m) * 64 + q * 8;
        bf16x8 a0 = *(const bf16x8*)qa;
        bf16x8 a1 = *(const bf16x8*)(qa + 32);
#pragma unroll
        for (int nb = 0; nb < 4; nb++) {
            int j = jb + nb * 16 + m;
            const unsigned short* kb = &KbB[(size_t)j * 64 + q * 8];
            bf16x8 b0 = *(const bf16x8*)kb;
            bf16x8 b1 = *(const bf16x8*)(kb + 32);
            f32x4 acc = {0.f, 0.f, 0.f, 0.f};
            acc = __builtin_amdgcn_mfma_f32_16x16x32_bf16(a0, b0, acc, 0, 0, 0);
            acc = __builtin_amdgcn_mfma_f32_16x16x32_bf16(a1, b1, acc, 0, 0, 0);
            int mj = maskPB[j];
#pragma unroll
            for (int g = 0; g < 4; g++) {
                float sv;
                if (!valid || mj == 2)   sv = -INFINITY;      // padding / no tile
                else if (mrow4[g] && mj) sv = acc[g] * 0.125f;
                else                     sv = -1e30f;         // reference's masked value
                sarr[tt][nb][g] = sv;
                lmax[g] = fmaxf(lmax[g], sv);
            }
        }
    }
#pragma unroll
    for (int g = 0; g < 4; g++) {
        float v = lmax[g];
#pragma unroll
        for (int o = 1; o < 16; o <<= 1) v = fmaxf(v, __shfl_xor(v, o));
        lmax[g] = v;
    }
    if (m == 0) {
#pragma unroll
        for (int g = 0; g < 4; g++) wred[wave][q * 4 + g] = lmax[g];
    }
    __syncthreads();

    // ---- phase 2: exp in regs, single P write, row sums (normalization deferred)
    float mx4[4], lsum[4] = {0.f, 0.f, 0.f, 0.f};
#pragma unroll
    for (int g = 0; g < 4; g++) {
        int i = q * 4 + g;
        mx4[g] = fmaxf(fmaxf(wred[0][i], wred[1][i]), fmaxf(wred[2][i], wred[3][i]));
    }
#pragma unroll
    for (int tt = 0; tt < MAXT; tt++) {
        int jt = wave + tt * 4;
        bool valid = (jt < tiles);
        int jb = jt * 64;
#pragma unroll
        for (int nb = 0; nb < 4; nb++) {
            int j = jb + nb * 16 + m;
#pragma unroll
            for (int g = 0; g < 4; g++) {
                float p = __expf(sarr[tt][nb][g] - mx4[g]);   // -inf -> 0
                lsum[g] += p;
                if (valid) S[q * 4 + g][j] = f2bf(p);
            }
        }
    }
#pragma unroll
    for (int g = 0; g < 4; g++) {
        float v = lsum[g];
#pragma unroll
        for (int o = 1; o < 16; o <<= 1) v += __shfl_xor(v, o);
        lsum[g] = v;
    }
    if (m == 0) {
#pragma unroll
        for (int g = 0; g < 4; g++) wsum[wave][q * 4 + g] = lsum[g];
    }
    __syncthreads();
    float sinv4[4];
#pragma unroll
    for (int g = 0; g < 4; g++) {
        int i = q * 4 + g;
        sinv4[g] = 1.0f / (wsum[0][i] + wsum[1][i] + wsum[2][i] + wsum[3][i]);
    }

    // ---- phase 3: out = P . V2t^T ; wave owns k-subtile; dual MFMA chains
    {
        int db = wave * 16;
        f32x4 ae = {0.f, 0.f, 0.f, 0.f};
        f32x4 ao = {0.f, 0.f, 0.f, 0.f};
        for (int jt = 0; jt < tiles; jt++) {
            int jb = jt * 64;
            bf16x8 a0 = *(const bf16x8*)&S[m][jb + q * 8];
            bf16x8 a1 = *(const bf16x8*)&S[m][jb + 32 + q * 8];
            const unsigned short* vb = V2B + (size_t)(db + m) * NP + jb + q * 8;
            bf16x8 b0 = *(const bf16x8*)vb;
            bf16x8 b1 = *(const bf16x8*)(vb + 32);
            ae = __builtin_amdgcn_mfma_f32_16x16x32_bf16(a0, b0, ae, 0, 0, 0);
            ao = __builtin_amdgcn_mfma_f32_16x16x32_bf16(a1, b1, ao, 0, 0, 0);
        }
#pragma unroll
        for (int g = 0; g < 4; g++) {
            int i = q * 4 + g;
            int tok = toki[i];
            if (tok >= 0)
                out[((size_t)b * NN + tok) * (NH * DKK) + h * DKK + db + m] = (ae[g] + ao[g]) * sinv4[g];
        }
    }
}

// ---------------------------------------------------------------- launch
extern "C" void kernel_launch(void* const* d_in, const int* in_sizes, int n_in,
                              void* d_out, int out_size, void* d_ws, size_t ws_size,
                              hipStream_t stream)
{
    const float* qr  = (const float*)d_in[0];
    const float* kr  = (const float*)d_in[1];
    const float* vr  = (const float*)d_in[2];
    const void* bsr  = d_in[3];
    const void* mkr  = d_in[4];
    const float* lr  = (const float*)d_in[5];
    const float* w1r = (const float*)d_in[6];
    const float* a1r = (const float*)d_in[7];
    const float* w2r = (const float*)d_in[8];
    const float* a2r = (const float*)d_in[9];
    float* out = (float*)d_out;

    char* w = (char*)d_ws;
    int* maskI    = (int*)w;
    int* perm     = maskI + BQ * NN;
    int* rowc     = perm + BQ * NP;
    int* startPad = rowc + BQ * NP;
    int* maskP    = startPad + 12;
    // bf16 buffers
    unsigned short* W1bt = (unsigned short*)(w + 65536);             // 1.11 MB
    unsigned short* W2bt = W1bt + (size_t)NCLS * NH * 4096;          // 1.11 MB
    unsigned short* Qb   = (unsigned short*)(w + 2359296);           // 2.75 MB each
    unsigned short* Kb   = Qb + (size_t)BQ * NH * NP * 64;
    unsigned short* Vb   = Kb + (size_t)BQ * NH * NP * 64;
    unsigned short* Lt   = (unsigned short*)(w + 10616832);          // 7.86 MB (dead after k_proj)
    unsigned short* Q2   = Lt;                                       // aliases Lt: 13.76 MB
    unsigned short* V2t  = (unsigned short*)(w + 24379392);          // 13.76 MB -> total ~38.1 MB
    // NOTE: Q2 written by k_qv2 strictly after k_proj's last Lt read (stream order)

    hipLaunchKernelGGL(k_setup, dim3(1), dim3(256), 0, stream,
                       bsr, mkr, maskI, perm, rowc, startPad, maskP);
    hipLaunchKernelGGL(k_prep, dim3(960 + 2 * NCLS * NH), dim3(256), 0, stream,
                       lr, Lt, w1r, w2r, a1r, a2r, W1bt, W2bt);
    hipLaunchKernelGGL(k_proj, dim3(NPT, 4, 6), dim3(256), 0, stream,
                       qr, kr, vr, Lt, perm, rowc, startPad, Qb, Kb, Vb);
    hipLaunchKernelGGL(k_qv2, dim3(NPT, NSEL, 32), dim3(256), 0, stream,
                       Qb, Vb, W1bt, W2bt, rowc, startPad, Q2, V2t);
    hipLaunchKernelGGL(k_attn, dim3(NP / 16, BQ * NH), dim3(256), 0, stream,
                       Q2, Kb, V2t, perm, rowc, startPad, maskI, maskP, out);
}